// Round 10
// baseline (50.568 us; speedup 1.0000x reference)
//
#include <hip/hip_runtime.h>

typedef __attribute__((ext_vector_type(8))) short bf16x8;
typedef __attribute__((ext_vector_type(4))) float f32x4;

constexpr int NCH = 18;     // 32-k chunks per K-quarter (K = 2304 symmetrized)

__device__ __forceinline__ unsigned short bf_rne(float f) {
  unsigned u = __float_as_uint(f);
  return (unsigned short)((u + 0x7fffu + ((u >> 16) & 1u)) >> 16);
}

// ---- prepass: symmetrize + pack W fragment-linear (verbatim r5/r8, verified) ----
__global__ __launch_bounds__(256) void wprep_kernel(const float* __restrict__ W,
                                                    unsigned short* __restrict__ Wp) {
  int e = blockIdx.x * 256 + threadIdx.x;   // 576*256 = 147456
  int c = e & 2047;
  int t2 = e >> 11;
  int kq = t2 / 18;
  int j = t2 - kq * 18;
  int nt = c >> 9;
  int q = (c >> 7) & 3;
  int r16 = (c >> 3) & 15;
  int el = c & 7;
  int o = nt * 16 + r16;
  int kl = j * 32 + q * 8 + el;
  int jblk = kl >> 6, i = kl & 63;
  int run1 = 8 - kq;
  int G, F;
  if (jblk < run1) { G = 7 - kq; F = jblk; } else { G = kq; F = jblk - run1; }
  int f = F * 8 + (i >> 3), g = G * 8 + (i & 7);
  float v = W[o * 4096 + f * 64 + g];
  if (F != G) v += W[o * 4096 + g * 64 + f];
  Wp[e] = bf_rne(v);
}

// ===== FULL quad: BYTE-IDENTICAL to round 8 (known 17.7 us warm) =====
__global__ __launch_bounds__(512, 2) void quad_kernel(const float* __restrict__ x,
                                                      const unsigned short* __restrict__ Wp,
                                                      float* __restrict__ out) {
  __shared__ float xT[8192];
  __shared__ alignas(16) float red[16384];

  const int t = threadIdx.x;
  const int lane = t & 63;
  const int wv = t >> 6;
  const int kq = wv & 3;
  const int ph = wv >> 2;
  const int q = lane >> 4;
  const int r16 = lane & 15;
  const int pxbase = blockIdx.x * 128;

  const char* wsrc = reinterpret_cast<const char*>(Wp) + kq * 73728 + lane * 16;

  bf16x8 bufs[4][4];
  auto loadB = [&](int j, int slot) {
#pragma unroll
    for (int nt = 0; nt < 4; ++nt)
      bufs[slot][nt] = *reinterpret_cast<const bf16x8*>(wsrc + j * 4096 + nt * 1024);
  };
  loadB(0, 0); loadB(1, 1); loadB(2, 2);

  {
    const float* xg_ = x + (long)pxbase * 64;
#pragma unroll
    for (int c = 0; c < 4; ++c) {
      int e4 = c * 512 + t;
      int px = e4 >> 4;
      int f0 = (e4 & 15) * 4;
      float4 v = *reinterpret_cast<const float4*>(xg_ + e4 * 4);
      xT[(f0 + 0) * 128 + (px ^ (f0 + 0))] = v.x;
      xT[(f0 + 1) * 128 + (px ^ (f0 + 1))] = v.y;
      xT[(f0 + 2) * 128 + (px ^ (f0 + 2))] = v.z;
      xT[(f0 + 3) * 128 + (px ^ (f0 + 3))] = v.w;
    }
  }
  __syncthreads();

  float xg[4][8];
  auto load_xg = [&](int G) {
#pragma unroll
    for (int m = 0; m < 4; ++m) {
      int px = ph * 64 + m * 16 + r16;
#pragma unroll
      for (int b = 0; b < 8; ++b) {
        int row = G * 8 + b;
        xg[m][b] = xT[row * 128 + (px ^ row)];
      }
    }
  };
  const int run1 = 8 - kq;
  load_xg(7 - kq);

  f32x4 acc[4][4] = {};

#pragma unroll
  for (int j = 0; j < NCH; ++j) {
    if (j + 3 < NCH) loadB(j + 3, (j + 3) & 3);
    if (j == 2 * run1) load_xg(kq);
    const int s = j & 1;
    const int blk = j >> 1;
    const int F = (blk < run1) ? blk : blk - run1;
    const int row = F * 8 + s * 4 + q;
    const int slot = j & 3;
    bf16x8 afr[4];
#pragma unroll
    for (int m = 0; m < 4; ++m) {
      float xf = xT[row * 128 + ((ph * 64 + m * 16 + r16) ^ row)];
      union { unsigned u[4]; bf16x8 v; } pk;
#pragma unroll
      for (int i = 0; i < 4; ++i) {
        unsigned p0 = __float_as_uint(xf * xg[m][2 * i]);
        unsigned p1 = __float_as_uint(xf * xg[m][2 * i + 1]);
        pk.u[i] = __builtin_amdgcn_perm(p1, p0, 0x07060302u);
      }
      afr[m] = pk.v;
    }
#pragma unroll
    for (int nt = 0; nt < 4; ++nt)
#pragma unroll
      for (int m = 0; m < 4; ++m)
        acc[m][nt] = __builtin_amdgcn_mfma_f32_16x16x32_bf16(afr[m], bufs[slot][nt],
                                                             acc[m][nt], 0, 0, 0);
  }

#pragma unroll
  for (int r = 0; r < 2; ++r) {
    if (r) __syncthreads();
#pragma unroll
    for (int mm = 0; mm < 2; ++mm)
#pragma unroll
      for (int nt = 0; nt < 4; ++nt)
        *reinterpret_cast<f32x4*>(red + ((ph * 2 + mm) * 4 + kq) * 1024 +
                                  (nt * 16 + r16) * 16 + q * 4) = acc[2 * r + mm][nt];
    __syncthreads();
    {
      const int mm2 = kq >> 1;
      const int h = kq & 1;
      const float* base = red + (ph * 2 + mm2) * 4 * 1024;
#pragma unroll
      for (int nh = 0; nh < 2; ++nh) {
        int nt = h * 2 + nh;
        int off = (nt * 16 + r16) * 16 + q * 4;
        f32x4 ssum = *reinterpret_cast<const f32x4*>(base + off);
#pragma unroll
        for (int w = 1; w < 4; ++w)
          ssum += *reinterpret_cast<const f32x4*>(base + w * 1024 + off);
        long prow = pxbase + ph * 64 + (2 * r + mm2) * 16 + q * 4;
#pragma unroll
        for (int b = 0; b < 4; ++b)
          out[(prow + b) * 64 + nt * 16 + r16] = ssum[b];
      }
    }
  }
}

// ===== STRIP variant: identical EXCEPT no in-loop loadB (slots pre-filled, =====
// ===== reused stale). Measures the compute/LDS/epilogue path in isolation. =====
// Writes garbage to out; the FULL quad launched after it overwrites everything.
__global__ __launch_bounds__(512, 2) void quad_strip(const float* __restrict__ x,
                                                     const unsigned short* __restrict__ Wp,
                                                     float* __restrict__ out) {
  __shared__ float xT[8192];
  __shared__ alignas(16) float red[16384];

  const int t = threadIdx.x;
  const int lane = t & 63;
  const int wv = t >> 6;
  const int kq = wv & 3;
  const int ph = wv >> 2;
  const int q = lane >> 4;
  const int r16 = lane & 15;
  const int pxbase = blockIdx.x * 128;

  const char* wsrc = reinterpret_cast<const char*>(Wp) + kq * 73728 + lane * 16;

  bf16x8 bufs[4][4];
  auto loadB = [&](int j, int slot) {
#pragma unroll
    for (int nt = 0; nt < 4; ++nt)
      bufs[slot][nt] = *reinterpret_cast<const bf16x8*>(wsrc + j * 4096 + nt * 1024);
  };
  loadB(0, 0); loadB(1, 1); loadB(2, 2); loadB(3, 3);   // prologue only

  {
    const float* xg_ = x + (long)pxbase * 64;
#pragma unroll
    for (int c = 0; c < 4; ++c) {
      int e4 = c * 512 + t;
      int px = e4 >> 4;
      int f0 = (e4 & 15) * 4;
      float4 v = *reinterpret_cast<const float4*>(xg_ + e4 * 4);
      xT[(f0 + 0) * 128 + (px ^ (f0 + 0))] = v.x;
      xT[(f0 + 1) * 128 + (px ^ (f0 + 1))] = v.y;
      xT[(f0 + 2) * 128 + (px ^ (f0 + 2))] = v.z;
      xT[(f0 + 3) * 128 + (px ^ (f0 + 3))] = v.w;
    }
  }
  __syncthreads();

  float xg[4][8];
  auto load_xg = [&](int G) {
#pragma unroll
    for (int m = 0; m < 4; ++m) {
      int px = ph * 64 + m * 16 + r16;
#pragma unroll
      for (int b = 0; b < 8; ++b) {
        int row = G * 8 + b;
        xg[m][b] = xT[row * 128 + (px ^ row)];
      }
    }
  };
  const int run1 = 8 - kq;
  load_xg(7 - kq);

  f32x4 acc[4][4] = {};

#pragma unroll
  for (int j = 0; j < NCH; ++j) {
    // NO in-loop loadB  <-- the single ablated element
    if (j == 2 * run1) load_xg(kq);
    const int s = j & 1;
    const int blk = j >> 1;
    const int F = (blk < run1) ? blk : blk - run1;
    const int row = F * 8 + s * 4 + q;
    const int slot = j & 3;
    bf16x8 afr[4];
#pragma unroll
    for (int m = 0; m < 4; ++m) {
      float xf = xT[row * 128 + ((ph * 64 + m * 16 + r16) ^ row)];
      union { unsigned u[4]; bf16x8 v; } pk;
#pragma unroll
      for (int i = 0; i < 4; ++i) {
        unsigned p0 = __float_as_uint(xf * xg[m][2 * i]);
        unsigned p1 = __float_as_uint(xf * xg[m][2 * i + 1]);
        pk.u[i] = __builtin_amdgcn_perm(p1, p0, 0x07060302u);
      }
      afr[m] = pk.v;
    }
#pragma unroll
    for (int nt = 0; nt < 4; ++nt)
#pragma unroll
      for (int m = 0; m < 4; ++m)
        acc[m][nt] = __builtin_amdgcn_mfma_f32_16x16x32_bf16(afr[m], bufs[slot][nt],
                                                             acc[m][nt], 0, 0, 0);
  }

#pragma unroll
  for (int r = 0; r < 2; ++r) {
    if (r) __syncthreads();
#pragma unroll
    for (int mm = 0; mm < 2; ++mm)
#pragma unroll
      for (int nt = 0; nt < 4; ++nt)
        *reinterpret_cast<f32x4*>(red + ((ph * 2 + mm) * 4 + kq) * 1024 +
                                  (nt * 16 + r16) * 16 + q * 4) = acc[2 * r + mm][nt];
    __syncthreads();
    {
      const int mm2 = kq >> 1;
      const int h = kq & 1;
      const float* base = red + (ph * 2 + mm2) * 4 * 1024;
#pragma unroll
      for (int nh = 0; nh < 2; ++nh) {
        int nt = h * 2 + nh;
        int off = (nt * 16 + r16) * 16 + q * 4;
        f32x4 ssum = *reinterpret_cast<const f32x4*>(base + off);
#pragma unroll
        for (int w = 1; w < 4; ++w)
          ssum += *reinterpret_cast<const f32x4*>(base + w * 1024 + off);
        long prow = pxbase + ph * 64 + (2 * r + mm2) * 16 + q * 4;
#pragma unroll
        for (int b = 0; b < 4; ++b)
          out[(prow + b) * 64 + nt * 16 + r16] = ssum[b];
      }
    }
  }
}

extern "C" void kernel_launch(void* const* d_in, const int* in_sizes, int n_in,
                              void* d_out, int out_size, void* d_ws, size_t ws_size,
                              hipStream_t stream) {
  const float* x = (const float*)d_in[0];
  const float* W = (const float*)d_in[1];
  float* out = (float*)d_out;
  unsigned short* Wp = (unsigned short*)d_ws;

  hipLaunchKernelGGL(wprep_kernel, dim3(576), dim3(256), 0, stream, W, Wp);
  // ABLATION: dur = 6.4 (wprep+overhead, from r8) + 2 x t_strip + 17.7 (full quad).
  // Strip output is garbage but fully overwritten by the final full quad.
  hipLaunchKernelGGL(quad_strip, dim3(256), dim3(512), 0, stream, x, Wp, out);
  hipLaunchKernelGGL(quad_strip, dim3(256), dim3(512), 0, stream, x, Wp, out);
  hipLaunchKernelGGL(quad_kernel, dim3(256), dim3(512), 0, stream, x, Wp, out);
}

// Round 11
// 28.702 us; speedup vs baseline: 1.7618x; 1.7618x over previous
//
#include <hip/hip_runtime.h>

typedef __attribute__((ext_vector_type(8))) short bf16x8;
typedef __attribute__((ext_vector_type(4))) float f32x4;
typedef __attribute__((ext_vector_type(2))) float f32x2;

constexpr int NCH = 18;     // 32-k chunks per K-quarter (K = 2304 symmetrized)

__device__ __forceinline__ unsigned short bf_rne(float f) {
  unsigned u = __float_as_uint(f);
  return (unsigned short)((u + 0x7fffu + ((u >> 16) & 1u)) >> 16);
}

// ---- prepass: symmetrize + pack W fragment-linear (verbatim r5/r8, verified) ----
__global__ __launch_bounds__(256) void wprep_kernel(const float* __restrict__ W,
                                                    unsigned short* __restrict__ Wp) {
  int e = blockIdx.x * 256 + threadIdx.x;   // 576*256 = 147456
  int c = e & 2047;
  int t2 = e >> 11;
  int kq = t2 / 18;
  int j = t2 - kq * 18;
  int nt = c >> 9;
  int q = (c >> 7) & 3;
  int r16 = (c >> 3) & 15;
  int el = c & 7;
  int o = nt * 16 + r16;
  int kl = j * 32 + q * 8 + el;
  int jblk = kl >> 6, i = kl & 63;
  int run1 = 8 - kq;
  int G, F;
  if (jblk < run1) { G = 7 - kq; F = jblk; } else { G = kq; F = jblk - run1; }
  int f = F * 8 + (i >> 3), g = G * 8 + (i & 7);
  float v = W[o * 4096 + f * 64 + g];
  if (F != G) v += W[o * 4096 + g * 64 + f];
  Wp[e] = bf_rne(v);
}

// xT swizzle with q-spread: px^row spreads r16; ^((row&3)<<4) splits q-groups
// across both 16-bank halves (xf reads -> 2-way = free). Bijective per row.
__device__ __forceinline__ int xidx(int row, int px) {
  return row * 128 + (px ^ row ^ ((row & 3) << 4));
}

// epilogue red index (words): 16B-aligned, bank-quad swizzled so each 16-lane
// phase of a b128 covers all 8 bank-quads (2 lanes/bank = free).
__device__ __forceinline__ int ridx(int reg, int row, int qq) {
  return reg * 1024 + (((row * 4 + qq) ^ (row & 7)) << 2);
}

// ---- main quad: 256 blocks x 512 thr (8 waves = 2 ph x 4 kq), r8 structure ----
__global__ __launch_bounds__(512, 2) void quad_kernel(const float* __restrict__ x,
                                                      const unsigned short* __restrict__ Wp,
                                                      float* __restrict__ out) {
  __shared__ float xT[8192];                 // [f 64][px 128] swizzled (32 KB)
  __shared__ alignas(16) float red[16384];   // 16 regions x 4 KB, quad-swizzled

  const int t = threadIdx.x;
  const int lane = t & 63;
  const int wv = t >> 6;        // 0..7
  const int kq = wv & 3;        // K quarter
  const int ph = wv >> 2;       // pixel half
  const int q = lane >> 4;
  const int r16 = lane & 15;
  const int pxbase = blockIdx.x * 128;

  const char* wsrc = reinterpret_cast<const char*>(Wp) + kq * 73728 + lane * 16;

  bf16x8 bufs[4][4];
  auto loadB = [&](int j, int slot) {
#pragma unroll
    for (int nt = 0; nt < 4; ++nt)
      bufs[slot][nt] = *reinterpret_cast<const bf16x8*>(wsrc + j * 4096 + nt * 1024);
  };
  loadB(0, 0); loadB(1, 1); loadB(2, 2);

  // x tile -> xT (transposed, q-spread swizzle; writes 2-way = free)
  {
    const float* xg_ = x + (long)pxbase * 64;
#pragma unroll
    for (int c = 0; c < 4; ++c) {
      int e4 = c * 512 + t;
      int px = e4 >> 4;            // 0..127
      int f0 = (e4 & 15) * 4;
      float4 v = *reinterpret_cast<const float4*>(xg_ + e4 * 4);
      xT[xidx(f0 + 0, px)] = v.x;
      xT[xidx(f0 + 1, px)] = v.y;
      xT[xidx(f0 + 2, px)] = v.z;
      xT[xidx(f0 + 3, px)] = v.w;
    }
  }
  __syncthreads();

  f32x2 xg2[4][4];   // per-lane g-chunk as float2 pairs (-> v_pk_mul_f32)
  auto load_xg = [&](int G) {
#pragma unroll
    for (int m = 0; m < 4; ++m) {
      int px = ph * 64 + m * 16 + r16;
#pragma unroll
      for (int i = 0; i < 4; ++i) {
        f32x2 p;
        p[0] = xT[xidx(G * 8 + 2 * i, px)];       // broadcast across q (free)
        p[1] = xT[xidx(G * 8 + 2 * i + 1, px)];
        xg2[m][i] = p;
      }
    }
  };
  const int run1 = 8 - kq;
  load_xg(7 - kq);

  f32x4 acc[4][4] = {};   // [m: 4x16 px][nt: 4x16 o]

#pragma unroll
  for (int j = 0; j < NCH; ++j) {
    if (j + 3 < NCH) loadB(j + 3, (j + 3) & 3);   // 4-slot ring, lead = 3 bodies
    if (j == 2 * run1) load_xg(kq);               // wave-uniform G-run switch
    const int s = j & 1;
    const int blk = j >> 1;
    const int F = (blk < run1) ? blk : blk - run1;
    const int row = F * 8 + s * 4 + q;
    const int slot = j & 3;
    bf16x8 afr[4];
#pragma unroll
    for (int m = 0; m < 4; ++m) {
      float xf = xT[xidx(row, ph * 64 + m * 16 + r16)];
      f32x2 xf2;
      xf2[0] = xf; xf2[1] = xf;
      union { unsigned u[4]; bf16x8 v; } pk;
#pragma unroll
      for (int i = 0; i < 4; ++i) {
        f32x2 p = xf2 * xg2[m][i];                // v_pk_mul_f32
        pk.u[i] = __builtin_amdgcn_perm(__float_as_uint(p[1]), __float_as_uint(p[0]),
                                        0x07060302u);   // truncate-pack 2x bf16
      }
      afr[m] = pk.v;
    }
#pragma unroll
    for (int nt = 0; nt < 4; ++nt)
#pragma unroll
      for (int m = 0; m < 4; ++m)
        acc[m][nt] = __builtin_amdgcn_mfma_f32_16x16x32_bf16(afr[m], bufs[slot][nt],
                                                             acc[m][nt], 0, 0, 0);
  }

  // ---- cross-kq reduction: 2 rounds of m-pairs, bank-quad-swizzled b128 ----
#pragma unroll
  for (int r = 0; r < 2; ++r) {
    if (r) __syncthreads();
#pragma unroll
    for (int mm = 0; mm < 2; ++mm)
#pragma unroll
      for (int nt = 0; nt < 4; ++nt)
        *reinterpret_cast<f32x4*>(red + ridx((ph * 2 + mm) * 4 + kq, nt * 16 + r16, q)) =
            acc[2 * r + mm][nt];
    __syncthreads();
    {
      const int mm2 = kq >> 1;
      const int h = kq & 1;
      const int rbase = (ph * 2 + mm2) * 4;
#pragma unroll
      for (int nh = 0; nh < 2; ++nh) {
        int nt = h * 2 + nh;
        f32x4 ssum = *reinterpret_cast<const f32x4*>(red + ridx(rbase, nt * 16 + r16, q));
#pragma unroll
        for (int w = 1; w < 4; ++w)
          ssum += *reinterpret_cast<const f32x4*>(red + ridx(rbase + w, nt * 16 + r16, q));
        long prow = pxbase + ph * 64 + (2 * r + mm2) * 16 + q * 4;   // D: row=q*4+b, col=r16
#pragma unroll
        for (int b = 0; b < 4; ++b)
          out[(prow + b) * 64 + nt * 16 + r16] = ssum[b];
      }
    }
  }
}

extern "C" void kernel_launch(void* const* d_in, const int* in_sizes, int n_in,
                              void* d_out, int out_size, void* d_ws, size_t ws_size,
                              hipStream_t stream) {
  const float* x = (const float*)d_in[0];
  const float* W = (const float*)d_in[1];
  float* out = (float*)d_out;
  unsigned short* Wp = (unsigned short*)d_ws;   // 288 KB packed fragment-linear bf16 W

  hipLaunchKernelGGL(wprep_kernel, dim3(576), dim3(256), 0, stream, W, Wp);
  hipLaunchKernelGGL(quad_kernel, dim3(256), dim3(512), 0, stream, x, Wp, out);
}